// Round 2
// baseline (565.030 us; speedup 1.0000x reference)
//
#include <hip/hip_runtime.h>

typedef unsigned short u16;
typedef __attribute__((ext_vector_type(8))) short short8;
typedef __attribute__((ext_vector_type(4))) float f32x4;

#define DIM    256
#define NE     8192
#define NROWS  8192
#define DECAY  0.1f
#define EPS_F  1e-5f
#define MARGIN 2.0f
#define CAP    2097152u

// output offsets (floats): quantize_st, embed_ind, loss, embed_normalized, cluster_size_new, embed_avg_new
#define OUT_Q    0
#define OUT_IND  2097152
#define OUT_LOSS 2105344
#define OUT_NORM 2105345
#define OUT_CSN  4202497
#define OUT_AVG  4210689

// ws offsets (bytes)
#define WS_KEYS  0         // u64[8192] final exact keys
#define WS_GKEYS 65536     // u64[8192] approx keys
#define WS_CNT   131072    // u32 candidate counter
#define WS_ENORM 131136    // f32[8192]
#define WS_SUM   163904    // f32[8192*256] transposed segment sums
#define WS_BINS  8552512   // f32[8192]
#define WS_LOSS  8585280   // f64
#define WS_S     8585288   // f64
#define WS_XB    8585296   // bf16[8192*256]  X in bf16
#define WS_ETB   12779600  // bf16[8192*256]  E^T in bf16 (k-contiguous)
#define WS_ET32  16973904  // f32[8192*256]   E^T in f32
#define WS_CAND  25362512  // u64[CAP]
#define WS_ZERO0 131072
#define WS_ZLEN  (WS_XB - WS_ZERO0)

__device__ __forceinline__ unsigned f32_ord(float f)
{
    unsigned u = __float_as_uint(f);
    return (u & 0x80000000u) ? ~u : (u | 0x80000000u);
}
__device__ __forceinline__ float f32_unord(unsigned v)
{
    return __uint_as_float((v & 0x80000000u) ? (v ^ 0x80000000u) : ~v);
}
__device__ __forceinline__ u16 bf16rne(float f)
{
    unsigned u = __float_as_uint(f);
    return (u16)((u + 0x7fffu + ((u >> 16) & 1u)) >> 16);
}
__device__ __forceinline__ void gload16(const void* g, void* l)
{
    __builtin_amdgcn_global_load_lds((const __attribute__((address_space(1))) unsigned int*)g,
                                     (__attribute__((address_space(3))) unsigned int*)l, 16, 0, 0);
}

__global__ __launch_bounds__(256) void vq_enorm_k(const float* __restrict__ E, float* __restrict__ enorm)
{
    const int j = blockIdx.x * blockDim.x + threadIdx.x;
    float s = 0.f;
    #pragma unroll 8
    for (int d = 0; d < DIM; ++d) {
        const float v = E[(size_t)d * NE + j];
        s += v * v;
    }
    enorm[j] = s;
}

__global__ __launch_bounds__(256) void vq_cvt_x_k(const float* __restrict__ X, u16* __restrict__ Xb)
{
    const int i = blockIdx.x * 256 + threadIdx.x; // 8 floats per thread
    const float4 a = ((const float4*)X)[i * 2];
    const float4 b = ((const float4*)X)[i * 2 + 1];
    short8 v;
    v[0] = (short)bf16rne(a.x); v[1] = (short)bf16rne(a.y);
    v[2] = (short)bf16rne(a.z); v[3] = (short)bf16rne(a.w);
    v[4] = (short)bf16rne(b.x); v[5] = (short)bf16rne(b.y);
    v[6] = (short)bf16rne(b.z); v[7] = (short)bf16rne(b.w);
    *(short8*)(Xb + (size_t)i * 8) = v;
}

// E [256][8192] f32  ->  ET32 [8192][256] f32 and ETb [8192][256] bf16
__global__ __launch_bounds__(256) void vq_trans_e_k(const float* __restrict__ E,
                                                    float* __restrict__ ET32,
                                                    u16* __restrict__ ETb)
{
    __shared__ float T[64][65];
    const int t = threadIdx.x;
    const int j0 = blockIdx.x * 64, d0 = blockIdx.y * 64;
    #pragma unroll
    for (int p = 0; p < 4; ++p) {
        const int dr = p * 16 + (t >> 4);
        const float4 v = *(const float4*)(E + (size_t)(d0 + dr) * NE + j0 + (t & 15) * 4);
        T[dr][(t & 15) * 4 + 0] = v.x; T[dr][(t & 15) * 4 + 1] = v.y;
        T[dr][(t & 15) * 4 + 2] = v.z; T[dr][(t & 15) * 4 + 3] = v.w;
    }
    __syncthreads();
    const int jc = t >> 2, seg = t & 3;
    const int j = j0 + jc;
    float vals[16];
    #pragma unroll
    for (int i = 0; i < 16; ++i) vals[i] = T[seg * 16 + i][jc];
    float4* o32 = (float4*)(ET32 + (size_t)j * DIM + d0 + seg * 16);
    o32[0] = make_float4(vals[0], vals[1], vals[2], vals[3]);
    o32[1] = make_float4(vals[4], vals[5], vals[6], vals[7]);
    o32[2] = make_float4(vals[8], vals[9], vals[10], vals[11]);
    o32[3] = make_float4(vals[12], vals[13], vals[14], vals[15]);
    short8 b0, b1;
    #pragma unroll
    for (int i = 0; i < 8; ++i) { b0[i] = (short)bf16rne(vals[i]); b1[i] = (short)bf16rne(vals[8 + i]); }
    *(short8*)(ETb + (size_t)j * DIM + d0 + seg * 16) = b0;
    *(short8*)(ETb + (size_t)j * DIM + d0 + seg * 16 + 8) = b1;
}

// approx distances via bf16 MFMA; wave-local row-min; emit candidates within MARGIN; approx global min via atomicMin
__global__ __launch_bounds__(256) void vq_dist_mfma_k(const u16* __restrict__ Xb,
                                                      const u16* __restrict__ ETb,
                                                      const float* __restrict__ enorm,
                                                      unsigned long long* __restrict__ gkeys,
                                                      unsigned long long* __restrict__ cand,
                                                      unsigned* __restrict__ cnt)
{
    __shared__ u16 As[4][128][8]; // [kseg][row][8k]
    __shared__ u16 Bs[4][128][8]; // [kseg][col][8k]

    const int tid = threadIdx.x;
    const int w = tid >> 6, l = tid & 63;
    const int wr = w >> 1, wc = w & 1;
    const int lane16 = l & 15, lgrp = l >> 4;
    const int row0 = blockIdx.x * 128, col0 = blockIdx.y * 128;

    f32x4 acc[4][4];
    #pragma unroll
    for (int mi = 0; mi < 4; ++mi)
        #pragma unroll
        for (int ni = 0; ni < 4; ++ni)
            acc[mi][ni] = {0.f, 0.f, 0.f, 0.f};

    const u16* gA = Xb + (size_t)(row0 + l) * DIM + w * 8;
    const u16* gB = ETb + (size_t)(col0 + l) * DIM + w * 8;

    #pragma unroll
    for (int kt = 0; kt < 8; ++kt) {
        gload16(gA + kt * 32,            &As[w][l][0]);
        gload16(gA + kt * 32 + 64 * DIM, &As[w][l + 64][0]);
        gload16(gB + kt * 32,            &Bs[w][l][0]);
        gload16(gB + kt * 32 + 64 * DIM, &Bs[w][l + 64][0]);
        __syncthreads();
        short8 af[4], bf[4];
        #pragma unroll
        for (int mi = 0; mi < 4; ++mi)
            af[mi] = *(const short8*)&As[lgrp][wr * 64 + mi * 16 + lane16][0];
        #pragma unroll
        for (int ni = 0; ni < 4; ++ni)
            bf[ni] = *(const short8*)&Bs[lgrp][wc * 64 + ni * 16 + lane16][0];
        #pragma unroll
        for (int mi = 0; mi < 4; ++mi)
            #pragma unroll
            for (int ni = 0; ni < 4; ++ni)
                acc[mi][ni] = __builtin_amdgcn_mfma_f32_16x16x32_bf16(af[mi], bf[ni], acc[mi][ni], 0, 0, 0);
        __syncthreads();
    }

    // d = enorm[col] - 2*dot, overwrite acc in place. C/D layout: col=lane&15, row=(lane>>4)*4+reg
    const int colbase = col0 + wc * 64 + lane16;
    float en[4];
    #pragma unroll
    for (int ni = 0; ni < 4; ++ni) en[ni] = enorm[colbase + ni * 16];
    #pragma unroll
    for (int mi = 0; mi < 4; ++mi)
        #pragma unroll
        for (int ni = 0; ni < 4; ++ni)
            acc[mi][ni] = en[ni] - 2.0f * acc[mi][ni];

    // wave-local per-row min over 64 cols -> emission threshold
    float thr[4][4];
    #pragma unroll
    for (int mi = 0; mi < 4; ++mi)
        #pragma unroll
        for (int reg = 0; reg < 4; ++reg) {
            float m = fminf(fminf(acc[mi][0][reg], acc[mi][1][reg]),
                            fminf(acc[mi][2][reg], acc[mi][3][reg]));
            m = fminf(m, __shfl_xor(m, 1, 16));
            m = fminf(m, __shfl_xor(m, 2, 16));
            m = fminf(m, __shfl_xor(m, 4, 16));
            m = fminf(m, __shfl_xor(m, 8, 16));
            thr[mi][reg] = m + MARGIN;
        }

    // count emissions, wave prefix-sum, one atomicAdd per wave
    int c = 0;
    #pragma unroll
    for (int mi = 0; mi < 4; ++mi)
        #pragma unroll
        for (int reg = 0; reg < 4; ++reg)
            #pragma unroll
            for (int ni = 0; ni < 4; ++ni)
                c += (acc[mi][ni][reg] <= thr[mi][reg]) ? 1 : 0;

    int incl = c;
    #pragma unroll
    for (int s = 1; s < 64; s <<= 1) {
        int t = __shfl_up(incl, s);
        if (l >= s) incl += t;
    }
    const int tot = __shfl(incl, 63);
    int base = 0;
    if (l == 63 && tot > 0) base = (int)atomicAdd(cnt, (unsigned)tot);
    base = __shfl(base, 63);
    unsigned pos = (unsigned)(base + incl - c);

    #pragma unroll
    for (int mi = 0; mi < 4; ++mi)
        #pragma unroll
        for (int reg = 0; reg < 4; ++reg) {
            const int row = row0 + wr * 64 + mi * 16 + lgrp * 4 + reg;
            #pragma unroll
            for (int ni = 0; ni < 4; ++ni) {
                const float d = acc[mi][ni][reg];
                if (d <= thr[mi][reg]) {
                    const int colj = colbase + ni * 16;
                    atomicMin(&gkeys[row], ((unsigned long long)f32_ord(d) << 32) | (unsigned)colj);
                    if (pos < CAP)
                        cand[pos] = ((unsigned long long)__float_as_uint(d) << 32)
                                    | (unsigned)((row << 13) | colj);
                    ++pos;
                }
            }
        }
}

// exact f32 re-ranking of candidates within MARGIN of the approx global min
__global__ __launch_bounds__(256) void vq_refine_k(const unsigned long long* __restrict__ cand,
                                                   const unsigned* __restrict__ cnt,
                                                   const unsigned long long* __restrict__ gkeys,
                                                   const float* __restrict__ X,
                                                   const float* __restrict__ ET32,
                                                   const float* __restrict__ enorm,
                                                   unsigned long long* __restrict__ keys)
{
    const int l = threadIdx.x & 63;
    const int wid = (blockIdx.x * 256 + threadIdx.x) >> 6;
    const int nw = (gridDim.x * 256) >> 6;
    const unsigned n = min(*cnt, CAP);
    for (unsigned i = wid; i < n; i += nw) {
        const unsigned long long e = cand[i];
        const unsigned pc = (unsigned)e;
        const int row = (int)(pc >> 13), colj = (int)(pc & 8191u);
        const float d = __uint_as_float((unsigned)(e >> 32));
        const float gmin = f32_unord((unsigned)(gkeys[row] >> 32));
        if (d > gmin + MARGIN) continue;
        const float4 xv = *(const float4*)(X + (size_t)row * DIM + l * 4);
        const float4 ev = *(const float4*)(ET32 + (size_t)colj * DIM + l * 4);
        float s = xv.x * ev.x + xv.y * ev.y + xv.z * ev.z + xv.w * ev.w;
        #pragma unroll
        for (int o = 32; o; o >>= 1) s += __shfl_xor(s, o);
        if (l == 0) {
            const float de = enorm[colj] - 2.f * s;
            atomicMin(&keys[row], ((unsigned long long)f32_ord(de) << 32) | (unsigned)colj);
        }
    }
}

__global__ __launch_bounds__(256) void vq_gather_stats_k(const float* __restrict__ X,
                                                         const float* __restrict__ ET32,
                                                         const unsigned long long* __restrict__ keys,
                                                         float* __restrict__ out_q,
                                                         float* __restrict__ out_ind,
                                                         float* __restrict__ ws_sum,
                                                         float* __restrict__ bins,
                                                         double* __restrict__ loss)
{
    const int tid = threadIdx.x;
    float lsum = 0.f;
    #pragma unroll
    for (int q = 0; q < 4; ++q) {
        const int row = blockIdx.x * 4 + q;
        const int j   = (int)(keys[row] & 0xffffffffull);
        const float x  = X[(size_t)row * DIM + tid];
        const float qv = ET32[(size_t)j * DIM + tid];
        out_q[(size_t)row * DIM + tid] = x + (qv - x);
        const float d = qv - x;
        lsum += d * d;
        atomicAdd(&ws_sum[(size_t)j * DIM + tid], x);
        if (tid == 0) {
            atomicAdd(&bins[j], 1.0f);
            out_ind[row] = (float)j;
        }
    }
    #pragma unroll
    for (int off = 32; off > 0; off >>= 1) lsum += __shfl_down(lsum, off);
    __shared__ double wred[4];
    if ((tid & 63) == 0) wred[tid >> 6] = (double)lsum;
    __syncthreads();
    if (tid == 0) atomicAdd(loss, wred[0] + wred[1] + wred[2] + wred[3]);
}

__global__ __launch_bounds__(256) void vq_csn_k(const float* __restrict__ cs,
                                                const float* __restrict__ bins,
                                                float* __restrict__ out_csn,
                                                float* __restrict__ out_loss,
                                                const double* __restrict__ loss,
                                                double* __restrict__ S)
{
    const int tid = threadIdx.x;
    const int i = blockIdx.x * 256 + tid;
    const float csn = cs[i] * DECAY + (1.0f - DECAY) * bins[i];
    out_csn[i] = csn;
    double v = (double)csn;
    #pragma unroll
    for (int off = 32; off > 0; off >>= 1) v += __shfl_down(v, off);
    __shared__ double wred[4];
    if ((tid & 63) == 0) wred[tid >> 6] = v;
    __syncthreads();
    if (tid == 0) atomicAdd(S, wred[0] + wred[1] + wred[2] + wred[3]);
    if (blockIdx.x == 0 && tid == 0) out_loss[0] = (float)(loss[0] * (1.0 / 2097152.0));
}

__global__ __launch_bounds__(256) void vq_embed_k(const float* __restrict__ EA,
                                                  const float* __restrict__ cs,
                                                  const float* __restrict__ bins,
                                                  const float* __restrict__ ws_sum,
                                                  const double* __restrict__ Sp,
                                                  float* __restrict__ out_norm,
                                                  float* __restrict__ out_avg)
{
    __shared__ float T[64][69];
    const int tid = threadIdx.x;
    const int j0 = blockIdx.x * 64;
    const int d0 = blockIdx.y * 64;
    #pragma unroll
    for (int p = 0; p < 4; ++p) {
        const int jr = (tid >> 4) + p * 16;
        const int dc = (tid & 15) * 4;
        const float4 v = *(const float4*)(ws_sum + (size_t)(j0 + jr) * DIM + d0 + dc);
        T[jr][dc + 0] = v.x; T[jr][dc + 1] = v.y; T[jr][dc + 2] = v.z; T[jr][dc + 3] = v.w;
    }
    __syncthreads();
    const double S = Sp[0];
    const float fac = (float)(S / (S + (double)NE * 1e-5));
    const int jc = tid & 63;
    const int j  = j0 + jc;
    const float csn  = cs[j] * DECAY + (1.0f - DECAY) * bins[j];
    const float cs_j = (csn + EPS_F) * fac;
    const int drb = (tid >> 6) * 16;
    #pragma unroll
    for (int p = 0; p < 16; ++p) {
        const int dr = drb + p;
        const float sum = T[jc][dr];
        const float ea  = EA[(size_t)(d0 + dr) * NE + j];
        const float ean = DECAY * ea + (1.0f - DECAY) * sum;
        out_avg[(size_t)(d0 + dr) * NE + j]  = ean;
        out_norm[(size_t)(d0 + dr) * NE + j] = ean / cs_j;
    }
}

extern "C" void kernel_launch(void* const* d_in, const int* in_sizes, int n_in,
                              void* d_out, int out_size, void* d_ws, size_t ws_size,
                              hipStream_t stream)
{
    const float* X  = (const float*)d_in[0];
    const float* E  = (const float*)d_in[1];
    const float* CS = (const float*)d_in[2];
    const float* EA = (const float*)d_in[3];
    float* out = (float*)d_out;
    char*  ws  = (char*)d_ws;

    unsigned long long* keys  = (unsigned long long*)(ws + WS_KEYS);
    unsigned long long* gkeys = (unsigned long long*)(ws + WS_GKEYS);
    unsigned*           cnt   = (unsigned*)(ws + WS_CNT);
    float*  enorm  = (float*)(ws + WS_ENORM);
    float*  ws_sum = (float*)(ws + WS_SUM);
    float*  bins   = (float*)(ws + WS_BINS);
    double* loss   = (double*)(ws + WS_LOSS);
    double* S      = (double*)(ws + WS_S);
    u16*    Xb     = (u16*)(ws + WS_XB);
    u16*    ETb    = (u16*)(ws + WS_ETB);
    float*  ET32   = (float*)(ws + WS_ET32);
    unsigned long long* cand = (unsigned long long*)(ws + WS_CAND);

    hipMemsetAsync(ws + WS_KEYS, 0xFF, 131072, stream);     // keys + gkeys -> u64 max
    hipMemsetAsync(ws + WS_ZERO0, 0, WS_ZLEN, stream);      // cnt, enorm, ws_sum, bins, loss, S

    vq_cvt_x_k<<<1024, 256, 0, stream>>>(X, Xb);
    vq_trans_e_k<<<dim3(NE / 64, DIM / 64), 256, 0, stream>>>(E, ET32, ETb);
    vq_enorm_k<<<NE / 256, 256, 0, stream>>>(E, enorm);
    vq_dist_mfma_k<<<dim3(NROWS / 128, NE / 128), 256, 0, stream>>>(Xb, ETb, enorm, gkeys, cand, cnt);
    vq_refine_k<<<512, 256, 0, stream>>>(cand, cnt, gkeys, X, ET32, enorm, keys);
    vq_gather_stats_k<<<NROWS / 4, 256, 0, stream>>>(X, ET32, keys, out + OUT_Q, out + OUT_IND, ws_sum, bins, loss);
    vq_csn_k<<<NE / 256, 256, 0, stream>>>(CS, bins, out + OUT_CSN, out + OUT_LOSS, loss, S);
    vq_embed_k<<<dim3(NE / 64, DIM / 64), 256, 0, stream>>>(EA, CS, bins, ws_sum, S, out + OUT_NORM, out + OUT_AVG);
}

// Round 3
// 203.261 us; speedup vs baseline: 2.7798x; 2.7798x over previous
//
#include <hip/hip_runtime.h>

typedef unsigned short u16;
typedef __attribute__((ext_vector_type(8))) short short8;
typedef __attribute__((ext_vector_type(4))) float f32x4;

#define DIM    256
#define NE     8192
#define NROWS  8192
#define DECAY  0.1f
#define EPS_F  1e-5f
#define CRANGES 16      // column ranges of 512
#define CTILES  32      // 16-col tiles per range
#define MQ      384u    // refine margin: 1.5 distance units in q-space (q step = 1/256)

// output offsets (floats): quantize_st, embed_ind, loss, embed_normalized, cluster_size_new, embed_avg_new
#define OUT_Q    0
#define OUT_IND  2097152
#define OUT_LOSS 2105344
#define OUT_NORM 2105345
#define OUT_CSN  4202497
#define OUT_AVG  4210689

// ws offsets (bytes)
#define WS_KEYS  0          // u64[8192] exact keys (written by refine, no init needed)
#define WS_CAND  65536      // u32[8192*32] top-2 per (row, range)
#define WS_ENORM 1114112    // f32[8192]
#define WS_SUM   1146880    // f32[8192*256] transposed segment sums
#define WS_BINS  9535488    // f32[8192]
#define WS_LOSS  9568256    // f64
#define WS_S     9568264    // f64
#define WS_XB    9568272    // bf16[8192*256]
#define WS_ETB   13762576   // bf16[8192*256] E^T (k-contiguous)
#define WS_ET32  17956880   // f32[8192*256]  E^T
#define WS_ZLEN  (9568272 - WS_SUM)   // zero sums, bins, loss, S

__device__ __forceinline__ unsigned f32_ord(float f)
{
    unsigned u = __float_as_uint(f);
    return (u & 0x80000000u) ? ~u : (u | 0x80000000u);
}
__device__ __forceinline__ u16 bf16rne(float f)
{
    unsigned u = __float_as_uint(f);
    return (u16)((u + 0x7fffu + ((u >> 16) & 1u)) >> 16);
}

__global__ __launch_bounds__(256) void vq_enorm_k(const float* __restrict__ E, float* __restrict__ enorm)
{
    const int j = blockIdx.x * blockDim.x + threadIdx.x;
    float s = 0.f;
    #pragma unroll 8
    for (int d = 0; d < DIM; ++d) {
        const float v = E[(size_t)d * NE + j];
        s += v * v;
    }
    enorm[j] = s;
}

__global__ __launch_bounds__(256) void vq_cvt_x_k(const float* __restrict__ X, u16* __restrict__ Xb)
{
    const int i = blockIdx.x * 256 + threadIdx.x;
    const float4 a = ((const float4*)X)[i * 2];
    const float4 b = ((const float4*)X)[i * 2 + 1];
    short8 v;
    v[0] = (short)bf16rne(a.x); v[1] = (short)bf16rne(a.y);
    v[2] = (short)bf16rne(a.z); v[3] = (short)bf16rne(a.w);
    v[4] = (short)bf16rne(b.x); v[5] = (short)bf16rne(b.y);
    v[6] = (short)bf16rne(b.z); v[7] = (short)bf16rne(b.w);
    *(short8*)(Xb + (size_t)i * 8) = v;
}

// E [256][8192] -> ET32 [8192][256] f32 and ETb [8192][256] bf16
__global__ __launch_bounds__(256) void vq_trans_e_k(const float* __restrict__ E,
                                                    float* __restrict__ ET32,
                                                    u16* __restrict__ ETb)
{
    __shared__ float T[64][65];
    const int t = threadIdx.x;
    const int j0 = blockIdx.x * 64, d0 = blockIdx.y * 64;
    #pragma unroll
    for (int p = 0; p < 4; ++p) {
        const int dr = p * 16 + (t >> 4);
        const float4 v = *(const float4*)(E + (size_t)(d0 + dr) * NE + j0 + (t & 15) * 4);
        T[dr][(t & 15) * 4 + 0] = v.x; T[dr][(t & 15) * 4 + 1] = v.y;
        T[dr][(t & 15) * 4 + 2] = v.z; T[dr][(t & 15) * 4 + 3] = v.w;
    }
    __syncthreads();
    const int jc = t >> 2, seg = t & 3;
    const int j = j0 + jc;
    float vals[16];
    #pragma unroll
    for (int i = 0; i < 16; ++i) vals[i] = T[seg * 16 + i][jc];
    float4* o32 = (float4*)(ET32 + (size_t)j * DIM + d0 + seg * 16);
    o32[0] = make_float4(vals[0], vals[1], vals[2], vals[3]);
    o32[1] = make_float4(vals[4], vals[5], vals[6], vals[7]);
    o32[2] = make_float4(vals[8], vals[9], vals[10], vals[11]);
    o32[3] = make_float4(vals[12], vals[13], vals[14], vals[15]);
    short8 b0, b1;
    #pragma unroll
    for (int i = 0; i < 8; ++i) { b0[i] = (short)bf16rne(vals[i]); b1[i] = (short)bf16rne(vals[8 + i]); }
    *(short8*)(ETb + (size_t)j * DIM + d0 + seg * 16) = b0;
    *(short8*)(ETb + (size_t)j * DIM + d0 + seg * 16 + 8) = b1;
}

// Row-stationary approx scan: wave owns 32 rows (A in regs), streams 512 cols from L2.
// Per-lane sorted top-2 keys per row-slot; key = (q19 << 13) | col, q = trunc((d+1024)*256).
// No LDS, no barriers, no atomics.
__global__ __launch_bounds__(256) void vq_scan_k(const u16* __restrict__ Xb,
                                                 const u16* __restrict__ ETb,
                                                 const float* __restrict__ enorm,
                                                 unsigned* __restrict__ cand)
{
    const int tid = threadIdx.x;
    const int w = tid >> 6, l = tid & 63;
    const int lane16 = l & 15, g = l >> 4;
    const int rowbase = blockIdx.x * 128 + w * 32;
    const int c0 = blockIdx.y * 512;

    // A fragments: af[sub][k8], lane l holds row (l&15), k-chunk (l>>4)*8
    short8 af[2][8];
    #pragma unroll
    for (int sub = 0; sub < 2; ++sub)
        #pragma unroll
        for (int k8 = 0; k8 < 8; ++k8)
            af[sub][k8] = *(const short8*)(Xb + (size_t)(rowbase + sub * 16 + lane16) * DIM + k8 * 32 + g * 8);

    unsigned s0[8], s1[8];
    #pragma unroll
    for (int i = 0; i < 8; ++i) { s0[i] = 0xFFFFFFFFu; s1[i] = 0xFFFFFFFFu; }

    for (int ct = 0; ct < CTILES; ++ct) {
        const int col = c0 + ct * 16 + lane16;
        const float en = enorm[col];
        const u16* bp = ETb + (size_t)col * DIM + g * 8;
        f32x4 acc0 = {0.f, 0.f, 0.f, 0.f}, acc1 = {0.f, 0.f, 0.f, 0.f};
        #pragma unroll
        for (int k8 = 0; k8 < 8; ++k8) {
            const short8 bf = *(const short8*)(bp + k8 * 32);
            acc0 = __builtin_amdgcn_mfma_f32_16x16x32_bf16(af[0][k8], bf, acc0, 0, 0, 0);
            acc1 = __builtin_amdgcn_mfma_f32_16x16x32_bf16(af[1][k8], bf, acc1, 0, 0, 0);
        }
        #pragma unroll
        for (int i = 0; i < 8; ++i) {
            const float a = (i < 4) ? acc0[i & 3] : acc1[i & 3];
            const float d = fmaf(-2.f, a, en);
            const float qf = fmaf(d, 256.f, 262144.f);   // (d + 1024) * 256
            unsigned q = (unsigned)qf;                   // trunc, negatives clamp to 0
            q = min(q, 0x7FFFFu);
            const unsigned key = (q << 13) | (unsigned)col;
            const unsigned t = max(s0[i], key);
            s0[i] = min(s0[i], key);
            s1[i] = min(s1[i], t);
        }
    }

    // merge sorted pairs across the 16 lanes of each g-group
    #pragma unroll
    for (int m = 1; m < 16; m <<= 1) {
        #pragma unroll
        for (int i = 0; i < 8; ++i) {
            const unsigned o0 = __shfl_xor(s0[i], m);
            const unsigned o1 = __shfl_xor(s1[i], m);
            const unsigned t0 = min(s0[i], o0);
            const unsigned t1 = min(max(s0[i], o0), min(s1[i], o1));
            s0[i] = t0; s1[i] = t1;
        }
    }
    if (lane16 == 0) {
        #pragma unroll
        for (int i = 0; i < 8; ++i) {
            const int row = rowbase + (i >> 2) * 16 + g * 4 + (i & 3);
            cand[((size_t)row * CRANGES + blockIdx.y) * 2 + 0] = s0[i];
            cand[((size_t)row * CRANGES + blockIdx.y) * 2 + 1] = s1[i];
        }
    }
}

// exact f32 re-rank of the <=32 kept candidates per row; one wave per row, no atomics
__global__ __launch_bounds__(256) void vq_refine_k(const unsigned* __restrict__ cand,
                                                   const float* __restrict__ X,
                                                   const float* __restrict__ ET32,
                                                   const float* __restrict__ enorm,
                                                   unsigned long long* __restrict__ keys)
{
    const int l = threadIdx.x & 63;
    const int row = blockIdx.x * 4 + (threadIdx.x >> 6);
    unsigned key = 0xFFFFFFFFu;
    if (l < 32) key = cand[(size_t)row * 32 + l];
    unsigned qmin = key;
    #pragma unroll
    for (int m = 32; m; m >>= 1) qmin = min(qmin, __shfl_xor(qmin, m));
    const unsigned qthr = (qmin >> 13) + MQ;
    unsigned long long mask = __ballot((l < 32) && ((key >> 13) <= qthr));
    const float4 xv = *(const float4*)(X + (size_t)row * DIM + l * 4);
    unsigned long long best = 0xFFFFFFFFFFFFFFFFull;
    while (mask) {
        const int src = __builtin_ctzll(mask);
        mask &= mask - 1;
        const int col = (int)(__shfl(key, src) & 8191u);
        const float4 ev = *(const float4*)(ET32 + (size_t)col * DIM + l * 4);
        float s = xv.x * ev.x + xv.y * ev.y + xv.z * ev.z + xv.w * ev.w;
        #pragma unroll
        for (int m = 32; m; m >>= 1) s += __shfl_xor(s, m);
        const float d = enorm[col] - 2.f * s;
        const unsigned long long k64 = ((unsigned long long)f32_ord(d) << 32) | (unsigned)col;
        best = (k64 < best) ? k64 : best;
    }
    if (l == 0) keys[row] = best;
}

__global__ __launch_bounds__(256) void vq_gather_stats_k(const float* __restrict__ X,
                                                         const float* __restrict__ ET32,
                                                         const unsigned long long* __restrict__ keys,
                                                         float* __restrict__ out_q,
                                                         float* __restrict__ out_ind,
                                                         float* __restrict__ ws_sum,
                                                         float* __restrict__ bins,
                                                         double* __restrict__ loss)
{
    const int tid = threadIdx.x;
    float lsum = 0.f;
    #pragma unroll
    for (int q = 0; q < 4; ++q) {
        const int row = blockIdx.x * 4 + q;
        const int j   = (int)(keys[row] & 0xffffffffull);
        const float x  = X[(size_t)row * DIM + tid];
        const float qv = ET32[(size_t)j * DIM + tid];
        out_q[(size_t)row * DIM + tid] = x + (qv - x);
        const float d = qv - x;
        lsum += d * d;
        atomicAdd(&ws_sum[(size_t)j * DIM + tid], x);
        if (tid == 0) {
            atomicAdd(&bins[j], 1.0f);
            out_ind[row] = (float)j;
        }
    }
    #pragma unroll
    for (int off = 32; off > 0; off >>= 1) lsum += __shfl_down(lsum, off);
    __shared__ double wred[4];
    if ((tid & 63) == 0) wred[tid >> 6] = (double)lsum;
    __syncthreads();
    if (tid == 0) atomicAdd(loss, wred[0] + wred[1] + wred[2] + wred[3]);
}

__global__ __launch_bounds__(256) void vq_csn_k(const float* __restrict__ cs,
                                                const float* __restrict__ bins,
                                                float* __restrict__ out_csn,
                                                float* __restrict__ out_loss,
                                                const double* __restrict__ loss,
                                                double* __restrict__ S)
{
    const int tid = threadIdx.x;
    const int i = blockIdx.x * 256 + tid;
    const float csn = cs[i] * DECAY + (1.0f - DECAY) * bins[i];
    out_csn[i] = csn;
    double v = (double)csn;
    #pragma unroll
    for (int off = 32; off > 0; off >>= 1) v += __shfl_down(v, off);
    __shared__ double wred[4];
    if ((tid & 63) == 0) wred[tid >> 6] = v;
    __syncthreads();
    if (tid == 0) atomicAdd(S, wred[0] + wred[1] + wred[2] + wred[3]);
    if (blockIdx.x == 0 && tid == 0) out_loss[0] = (float)(loss[0] * (1.0 / 2097152.0));
}

__global__ __launch_bounds__(256) void vq_embed_k(const float* __restrict__ EA,
                                                  const float* __restrict__ cs,
                                                  const float* __restrict__ bins,
                                                  const float* __restrict__ ws_sum,
                                                  const double* __restrict__ Sp,
                                                  float* __restrict__ out_norm,
                                                  float* __restrict__ out_avg)
{
    __shared__ float T[64][69];
    const int tid = threadIdx.x;
    const int j0 = blockIdx.x * 64;
    const int d0 = blockIdx.y * 64;
    #pragma unroll
    for (int p = 0; p < 4; ++p) {
        const int jr = (tid >> 4) + p * 16;
        const int dc = (tid & 15) * 4;
        const float4 v = *(const float4*)(ws_sum + (size_t)(j0 + jr) * DIM + d0 + dc);
        T[jr][dc + 0] = v.x; T[jr][dc + 1] = v.y; T[jr][dc + 2] = v.z; T[jr][dc + 3] = v.w;
    }
    __syncthreads();
    const double S = Sp[0];
    const float fac = (float)(S / (S + (double)NE * 1e-5));
    const int jc = tid & 63;
    const int j  = j0 + jc;
    const float csn  = cs[j] * DECAY + (1.0f - DECAY) * bins[j];
    const float cs_j = (csn + EPS_F) * fac;
    const int drb = (tid >> 6) * 16;
    #pragma unroll
    for (int p = 0; p < 16; ++p) {
        const int dr = drb + p;
        const float sum = T[jc][dr];
        const float ea  = EA[(size_t)(d0 + dr) * NE + j];
        const float ean = DECAY * ea + (1.0f - DECAY) * sum;
        out_avg[(size_t)(d0 + dr) * NE + j]  = ean;
        out_norm[(size_t)(d0 + dr) * NE + j] = ean / cs_j;
    }
}

extern "C" void kernel_launch(void* const* d_in, const int* in_sizes, int n_in,
                              void* d_out, int out_size, void* d_ws, size_t ws_size,
                              hipStream_t stream)
{
    const float* X  = (const float*)d_in[0];
    const float* E  = (const float*)d_in[1];
    const float* CS = (const float*)d_in[2];
    const float* EA = (const float*)d_in[3];
    float* out = (float*)d_out;
    char*  ws  = (char*)d_ws;

    unsigned long long* keys = (unsigned long long*)(ws + WS_KEYS);
    unsigned* cand  = (unsigned*)(ws + WS_CAND);
    float*  enorm  = (float*)(ws + WS_ENORM);
    float*  ws_sum = (float*)(ws + WS_SUM);
    float*  bins   = (float*)(ws + WS_BINS);
    double* loss   = (double*)(ws + WS_LOSS);
    double* S      = (double*)(ws + WS_S);
    u16*    Xb     = (u16*)(ws + WS_XB);
    u16*    ETb    = (u16*)(ws + WS_ETB);
    float*  ET32   = (float*)(ws + WS_ET32);

    hipMemsetAsync(ws + WS_SUM, 0, WS_ZLEN, stream);   // ws_sum, bins, loss, S

    vq_cvt_x_k<<<1024, 256, 0, stream>>>(X, Xb);
    vq_trans_e_k<<<dim3(NE / 64, DIM / 64), 256, 0, stream>>>(E, ET32, ETb);
    vq_enorm_k<<<NE / 256, 256, 0, stream>>>(E, enorm);
    vq_scan_k<<<dim3(NROWS / 128, CRANGES), 256, 0, stream>>>(Xb, ETb, enorm, cand);
    vq_refine_k<<<NROWS / 4, 256, 0, stream>>>(cand, X, ET32, enorm, keys);
    vq_gather_stats_k<<<NROWS / 4, 256, 0, stream>>>(X, ET32, keys, out + OUT_Q, out + OUT_IND, ws_sum, bins, loss);
    vq_csn_k<<<NE / 256, 256, 0, stream>>>(CS, bins, out + OUT_CSN, out + OUT_LOSS, loss, S);
    vq_embed_k<<<dim3(NE / 64, DIM / 64), 256, 0, stream>>>(EA, CS, bins, ws_sum, S, out + OUT_NORM, out + OUT_AVG);
}

// Round 5
// 132.921 us; speedup vs baseline: 4.2509x; 1.5292x over previous
//
#include <hip/hip_runtime.h>

typedef unsigned short u16;
typedef __attribute__((ext_vector_type(8))) short short8;
typedef __attribute__((ext_vector_type(4))) float f32x4;

#define DIM    256
#define NE     8192
#define NROWS  8192
#define DECAY  0.1f
#define EPS_F  1e-5f
#define CRANGES 16      // column ranges of 512
#define CTILES  32      // 16-col tiles per range
#define MQ      384u    // refine margin: 1.5 distance units (q step = 1/256)

// output offsets (floats): quantize_st, embed_ind, loss, embed_normalized, cluster_size_new, embed_avg_new
#define OUT_Q    0
#define OUT_IND  2097152
#define OUT_LOSS 2105344
#define OUT_NORM 2105345
#define OUT_CSN  4202497
#define OUT_AVG  4210689

// ws offsets (bytes)
#define WS_KEYS  0          // u64[8192] exact keys (refine writes unconditionally)
#define WS_CAND  65536      // u32[8192*32] top-2 per (row, range)
#define WS_ENORM 1114112    // f32[8192]
#define WS_BASEQ 1146880    // f32[8192]  (enorm + 1024) * 256
#define WS_SUM   1179648    // f32[8192*256] transposed segment sums
#define WS_BINS  9568256    // f32[8192]
#define WS_LOSS  9601024    // f64
#define WS_S     9601032    // f64
#define WS_XB    9601040    // bf16[8192*256]
#define WS_ETB   13795344   // bf16[8192*256] E^T (k-contiguous)
#define WS_ET32  17989648   // f32[8192*256]  E^T
#define WS_ZLEN  (WS_XB - WS_SUM)   // zero sums, bins, loss, S

__device__ __forceinline__ unsigned f32_ord(float f)
{
    unsigned u = __float_as_uint(f);
    return (u & 0x80000000u) ? ~u : (u | 0x80000000u);
}
__device__ __forceinline__ u16 bf16rne(float f)
{
    unsigned u = __float_as_uint(f);
    return (u16)((u + 0x7fffu + ((u >> 16) & 1u)) >> 16);
}
__device__ __forceinline__ void gload16(const void* g, void* l)
{
    __builtin_amdgcn_global_load_lds((const __attribute__((address_space(1))) unsigned int*)g,
                                     (__attribute__((address_space(3))) unsigned int*)l, 16, 0, 0);
}

__global__ __launch_bounds__(256) void vq_enorm_k(const float* __restrict__ E,
                                                  float* __restrict__ enorm,
                                                  float* __restrict__ baseq)
{
    const int j = blockIdx.x * blockDim.x + threadIdx.x;
    float s = 0.f;
    #pragma unroll 8
    for (int d = 0; d < DIM; ++d) {
        const float v = E[(size_t)d * NE + j];
        s += v * v;
    }
    enorm[j] = s;
    baseq[j] = (s + 1024.f) * 256.f;
}

__global__ __launch_bounds__(256) void vq_cvt_x_k(const float* __restrict__ X, u16* __restrict__ Xb)
{
    const int i = blockIdx.x * 256 + threadIdx.x;
    const float4 a = ((const float4*)X)[i * 2];
    const float4 b = ((const float4*)X)[i * 2 + 1];
    short8 v;
    v[0] = (short)bf16rne(a.x); v[1] = (short)bf16rne(a.y);
    v[2] = (short)bf16rne(a.z); v[3] = (short)bf16rne(a.w);
    v[4] = (short)bf16rne(b.x); v[5] = (short)bf16rne(b.y);
    v[6] = (short)bf16rne(b.z); v[7] = (short)bf16rne(b.w);
    *(short8*)(Xb + (size_t)i * 8) = v;
}

// E [256][8192] -> ET32 [8192][256] f32 and ETb [8192][256] bf16
__global__ __launch_bounds__(256) void vq_trans_e_k(const float* __restrict__ E,
                                                    float* __restrict__ ET32,
                                                    u16* __restrict__ ETb)
{
    __shared__ float T[64][65];
    const int t = threadIdx.x;
    const int j0 = blockIdx.x * 64, d0 = blockIdx.y * 64;
    #pragma unroll
    for (int p = 0; p < 4; ++p) {
        const int dr = p * 16 + (t >> 4);
        const float4 v = *(const float4*)(E + (size_t)(d0 + dr) * NE + j0 + (t & 15) * 4);
        T[dr][(t & 15) * 4 + 0] = v.x; T[dr][(t & 15) * 4 + 1] = v.y;
        T[dr][(t & 15) * 4 + 2] = v.z; T[dr][(t & 15) * 4 + 3] = v.w;
    }
    __syncthreads();
    const int jc = t >> 2, seg = t & 3;
    const int j = j0 + jc;
    float vals[16];
    #pragma unroll
    for (int i = 0; i < 16; ++i) vals[i] = T[seg * 16 + i][jc];
    float4* o32 = (float4*)(ET32 + (size_t)j * DIM + d0 + seg * 16);
    o32[0] = make_float4(vals[0], vals[1], vals[2], vals[3]);
    o32[1] = make_float4(vals[4], vals[5], vals[6], vals[7]);
    o32[2] = make_float4(vals[8], vals[9], vals[10], vals[11]);
    o32[3] = make_float4(vals[12], vals[13], vals[14], vals[15]);
    short8 b0, b1;
    #pragma unroll
    for (int i = 0; i < 8; ++i) { b0[i] = (short)bf16rne(vals[i]); b1[i] = (short)bf16rne(vals[8 + i]); }
    *(short8*)(ETb + (size_t)j * DIM + d0 + seg * 16) = b0;
    *(short8*)(ETb + (size_t)j * DIM + d0 + seg * 16 + 8) = b1;
}

// Row-stationary approx scan, 2-phase LDS pipeline:
//   block = 4 waves = 128 rows x 512-col range; A frags in regs for the whole kernel.
//   Per 16-col tile, the 8KB B-tile is staged ONCE per block via global_load_lds into a
//   lane-linear slice layout that IS the MFMA B-fragment layout (ds_read_b128 @ lane*16,
//   conflict-free). STAGE(next) -> compute(cur) -> vmcnt(0) -> barrier (guide T3-minimum).
//   Per-lane sorted top-2 keys per row-slot; key = (q19 << 13) | col. No atomics.
__global__ __launch_bounds__(256) void vq_scan_k(const u16* __restrict__ Xb,
                                                 const u16* __restrict__ ETb,
                                                 const float* __restrict__ baseq,
                                                 unsigned* __restrict__ cand)
{
    __shared__ u16 Bs[2][8][512]; // [buf][k8-slice][16 cols x 32 k, lane-linear], 8KB/buf

    const int tid = threadIdx.x;
    const int w = tid >> 6, l = tid & 63;
    const int lane16 = l & 15, g = l >> 4;
    const int rowbase = blockIdx.x * 128 + w * 32;
    const int c0 = blockIdx.y * 512;

    // A fragments: lane holds row (l&15) of sub-tile, k-chunk (l>>4)*8, for k8=0..7
    short8 af[2][8];
    #pragma unroll
    for (int sub = 0; sub < 2; ++sub)
        #pragma unroll
        for (int k8 = 0; k8 < 8; ++k8)
            af[sub][k8] = *(const short8*)(Xb + (size_t)(rowbase + sub * 16 + lane16) * DIM + k8 * 32 + g * 8);

    unsigned s0[8], s1[8];
    #pragma unroll
    for (int i = 0; i < 8; ++i) { s0[i] = 0xFFFFFFFFu; s1[i] = 0xFFFFFFFFu; }

    // staging source: wave w owns slices k8 = 2w, 2w+1; lane (g,col) fetches its own 16B
    const u16* gsrc = ETb + (size_t)(c0 + lane16) * DIM + (size_t)w * 64 + g * 8;

    // prologue: stage tile 0
    gload16(gsrc,      &Bs[0][2 * w + 0][0]);
    gload16(gsrc + 32, &Bs[0][2 * w + 1][0]);
    asm volatile("s_waitcnt vmcnt(0)" ::: "memory");
    __builtin_amdgcn_s_barrier();

    int buf = 0;
    #pragma unroll 1
    for (int ct = 0; ct < CTILES; ++ct) {
        if (ct + 1 < CTILES) { // stage next tile into the other buffer (read-done by prev barrier)
            const u16* p = gsrc + (size_t)(ct + 1) * 16 * DIM;
            gload16(p,      &Bs[buf ^ 1][2 * w + 0][0]);
            gload16(p + 32, &Bs[buf ^ 1][2 * w + 1][0]);
        }
        const int col = c0 + ct * 16 + lane16;
        const float bq = baseq[col];
        f32x4 acc0 = {0.f, 0.f, 0.f, 0.f}, acc1 = {0.f, 0.f, 0.f, 0.f};
        #pragma unroll
        for (int k8 = 0; k8 < 8; ++k8) {
            const short8 bf = *(const short8*)&Bs[buf][k8][l * 8];
            acc0 = __builtin_amdgcn_mfma_f32_16x16x32_bf16(af[0][k8], bf, acc0, 0, 0, 0);
            acc1 = __builtin_amdgcn_mfma_f32_16x16x32_bf16(af[1][k8], bf, acc1, 0, 0, 0);
        }
        #pragma unroll
        for (int i = 0; i < 8; ++i) {
            const float a = (i < 4) ? acc0[i] : acc1[i - 4];
            const float qf = fmaf(a, -512.f, bq);       // (enorm - 2*dot + 1024) * 256
            unsigned q = (unsigned)qf;
            q = min(q, 0x7FFFFu);
            const unsigned key = (q << 13) | (unsigned)col;
            const unsigned t = max(s0[i], key);
            s0[i] = min(s0[i], key);
            s1[i] = min(s1[i], t);
        }
        asm volatile("s_waitcnt vmcnt(0)" ::: "memory");
        __builtin_amdgcn_s_barrier();
        buf ^= 1;
    }

    // merge sorted pairs across the 16 lanes of each g-group
    #pragma unroll
    for (int m = 1; m < 16; m <<= 1) {
        #pragma unroll
        for (int i = 0; i < 8; ++i) {
            const unsigned o0 = __shfl_xor(s0[i], m);
            const unsigned o1 = __shfl_xor(s1[i], m);
            const unsigned t0 = min(s0[i], o0);
            const unsigned t1 = min(max(s0[i], o0), min(s1[i], o1));
            s0[i] = t0; s1[i] = t1;
        }
    }
    if (lane16 == 0) {
        #pragma unroll
        for (int i = 0; i < 8; ++i) {
            const int row = rowbase + (i >> 2) * 16 + g * 4 + (i & 3);
            cand[((size_t)row * CRANGES + blockIdx.y) * 2 + 0] = s0[i];
            cand[((size_t)row * CRANGES + blockIdx.y) * 2 + 1] = s1[i];
        }
    }
}

// exact f32 re-rank of the <=32 kept candidates per row; one wave per row, no atomics
__global__ __launch_bounds__(256) void vq_refine_k(const unsigned* __restrict__ cand,
                                                   const float* __restrict__ X,
                                                   const float* __restrict__ ET32,
                                                   const float* __restrict__ enorm,
                                                   unsigned long long* __restrict__ keys)
{
    const int l = threadIdx.x & 63;
    const int row = blockIdx.x * 4 + (threadIdx.x >> 6);
    unsigned key = 0xFFFFFFFFu;
    if (l < 32) key = cand[(size_t)row * 32 + l];
    unsigned qmin = key;
    #pragma unroll
    for (int m = 32; m; m >>= 1) qmin = min(qmin, __shfl_xor(qmin, m));
    const unsigned qthr = (qmin >> 13) + MQ;
    unsigned long long mask = __ballot((l < 32) && ((key >> 13) <= qthr));
    const float4 xv = *(const float4*)(X + (size_t)row * DIM + l * 4);
    unsigned long long best = 0xFFFFFFFFFFFFFFFFull;
    while (mask) {
        const int src = __builtin_ctzll(mask);
        mask &= mask - 1;
        const int col = (int)(__shfl(key, src) & 8191u);
        const float4 ev = *(const float4*)(ET32 + (size_t)col * DIM + l * 4);
        float s = xv.x * ev.x + xv.y * ev.y + xv.z * ev.z + xv.w * ev.w;
        #pragma unroll
        for (int m = 32; m; m >>= 1) s += __shfl_xor(s, m);
        const float d = enorm[col] - 2.f * s;
        const unsigned long long k64 = ((unsigned long long)f32_ord(d) << 32) | (unsigned)col;
        best = (k64 < best) ? k64 : best;
    }
    if (l == 0) keys[row] = best;
}

__global__ __launch_bounds__(256) void vq_gather_stats_k(const float* __restrict__ X,
                                                         const float* __restrict__ ET32,
                                                         const unsigned long long* __restrict__ keys,
                                                         float* __restrict__ out_q,
                                                         float* __restrict__ out_ind,
                                                         float* __restrict__ ws_sum,
                                                         float* __restrict__ bins,
                                                         double* __restrict__ loss)
{
    const int tid = threadIdx.x;
    float lsum = 0.f;
    #pragma unroll
    for (int q = 0; q < 4; ++q) {
        const int row = blockIdx.x * 4 + q;
        const int j   = (int)(keys[row] & 0xffffffffull);
        const float x  = X[(size_t)row * DIM + tid];
        const float qv = ET32[(size_t)j * DIM + tid];
        out_q[(size_t)row * DIM + tid] = x + (qv - x);
        const float d = qv - x;
        lsum += d * d;
        atomicAdd(&ws_sum[(size_t)j * DIM + tid], x);
        if (tid == 0) {
            atomicAdd(&bins[j], 1.0f);
            out_ind[row] = (float)j;
        }
    }
    #pragma unroll
    for (int off = 32; off > 0; off >>= 1) lsum += __shfl_down(lsum, off);
    __shared__ double wred[4];
    if ((tid & 63) == 0) wred[tid >> 6] = (double)lsum;
    __syncthreads();
    if (tid == 0) atomicAdd(loss, wred[0] + wred[1] + wred[2] + wred[3]);
}

__global__ __launch_bounds__(256) void vq_csn_k(const float* __restrict__ cs,
                                                const float* __restrict__ bins,
                                                float* __restrict__ out_csn,
                                                float* __restrict__ out_loss,
                                                const double* __restrict__ loss,
                                                double* __restrict__ S)
{
    const int tid = threadIdx.x;
    const int i = blockIdx.x * 256 + tid;
    const float csn = cs[i] * DECAY + (1.0f - DECAY) * bins[i];
    out_csn[i] = csn;
    double v = (double)csn;
    #pragma unroll
    for (int off = 32; off > 0; off >>= 1) v += __shfl_down(v, off);
    __shared__ double wred[4];
    if ((tid & 63) == 0) wred[tid >> 6] = v;
    __syncthreads();
    if (tid == 0) atomicAdd(S, wred[0] + wred[1] + wred[2] + wred[3]);
    if (blockIdx.x == 0 && tid == 0) out_loss[0] = (float)(loss[0] * (1.0 / 2097152.0));
}

__global__ __launch_bounds__(256) void vq_embed_k(const float* __restrict__ EA,
                                                  const float* __restrict__ cs,
                                                  const float* __restrict__ bins,
                                                  const float* __restrict__ ws_sum,
                                                  const double* __restrict__ Sp,
                                                  float* __restrict__ out_norm,
                                                  float* __restrict__ out_avg)
{
    __shared__ float T[64][69];
    const int tid = threadIdx.x;
    const int j0 = blockIdx.x * 64;
    const int d0 = blockIdx.y * 64;
    #pragma unroll
    for (int p = 0; p < 4; ++p) {
        const int jr = (tid >> 4) + p * 16;
        const int dc = (tid & 15) * 4;
        const float4 v = *(const float4*)(ws_sum + (size_t)(j0 + jr) * DIM + d0 + dc);
        T[jr][dc + 0] = v.x; T[jr][dc + 1] = v.y; T[jr][dc + 2] = v.z; T[jr][dc + 3] = v.w;
    }
    __syncthreads();
    const double S = Sp[0];
    const float fac = (float)(S / (S + (double)NE * 1e-5));
    const int jc = tid & 63;
    const int j  = j0 + jc;
    const float csn  = cs[j] * DECAY + (1.0f - DECAY) * bins[j];
    const float cs_j = (csn + EPS_F) * fac;
    const int drb = (tid >> 6) * 16;
    #pragma unroll
    for (int p = 0; p < 16; ++p) {
        const int dr = drb + p;
        const float sum = T[jc][dr];
        const float ea  = EA[(size_t)(d0 + dr) * NE + j];
        const float ean = DECAY * ea + (1.0f - DECAY) * sum;
        out_avg[(size_t)(d0 + dr) * NE + j]  = ean;
        out_norm[(size_t)(d0 + dr) * NE + j] = ean / cs_j;
    }
}

extern "C" void kernel_launch(void* const* d_in, const int* in_sizes, int n_in,
                              void* d_out, int out_size, void* d_ws, size_t ws_size,
                              hipStream_t stream)
{
    const float* X  = (const float*)d_in[0];
    const float* E  = (const float*)d_in[1];
    const float* CS = (const float*)d_in[2];
    const float* EA = (const float*)d_in[3];
    float* out = (float*)d_out;
    char*  ws  = (char*)d_ws;

    unsigned long long* keys = (unsigned long long*)(ws + WS_KEYS);
    unsigned* cand  = (unsigned*)(ws + WS_CAND);
    float*  enorm  = (float*)(ws + WS_ENORM);
    float*  baseq  = (float*)(ws + WS_BASEQ);
    float*  ws_sum = (float*)(ws + WS_SUM);
    float*  bins   = (float*)(ws + WS_BINS);
    double* loss   = (double*)(ws + WS_LOSS);
    double* S      = (double*)(ws + WS_S);
    u16*    Xb     = (u16*)(ws + WS_XB);
    u16*    ETb    = (u16*)(ws + WS_ETB);
    float*  ET32   = (float*)(ws + WS_ET32);

    hipMemsetAsync(ws + WS_SUM, 0, WS_ZLEN, stream);   // ws_sum, bins, loss, S

    vq_cvt_x_k<<<1024, 256, 0, stream>>>(X, Xb);
    vq_trans_e_k<<<dim3(NE / 64, DIM / 64), 256, 0, stream>>>(E, ET32, ETb);
    vq_enorm_k<<<NE / 256, 256, 0, stream>>>(E, enorm, baseq);
    vq_scan_k<<<dim3(NROWS / 128, CRANGES), 256, 0, stream>>>(Xb, ETb, baseq, cand);
    vq_refine_k<<<NROWS / 4, 256, 0, stream>>>(cand, X, ET32, enorm, keys);
    vq_gather_stats_k<<<NROWS / 4, 256, 0, stream>>>(X, ET32, keys, out + OUT_Q, out + OUT_IND, ws_sum, bins, loss);
    vq_csn_k<<<NE / 256, 256, 0, stream>>>(CS, bins, out + OUT_CSN, out + OUT_LOSS, loss, S);
    vq_embed_k<<<dim3(NE / 64, DIM / 64), 256, 0, stream>>>(EA, CS, bins, ws_sum, S, out + OUT_NORM, out + OUT_AVG);
}

// Round 6
// 116.076 us; speedup vs baseline: 4.8677x; 1.1451x over previous
//
#include <hip/hip_runtime.h>

typedef unsigned short u16;
typedef __attribute__((ext_vector_type(8))) short short8;
typedef __attribute__((ext_vector_type(4))) float f32x4;

#define DIM    256
#define NE     8192
#define NROWS  8192
#define DECAY  0.1f
#define EPS_F  1e-5f
#define CRANGES 16      // column ranges of 512
#define CTILES  32      // 16-col tiles per range
#define MQ      384u    // refine margin: 1.5 distance units (q step = 1/256)

// output offsets (floats): quantize_st, embed_ind, loss, embed_normalized, cluster_size_new, embed_avg_new
#define OUT_Q    0
#define OUT_IND  2097152
#define OUT_LOSS 2105344
#define OUT_NORM 2105345
#define OUT_CSN  4202497
#define OUT_AVG  4210689

// ws offsets (bytes)
#define WS_CAND  65536      // u32[8192*32] top-2 per (row, range)
#define WS_ENORM 1114112    // f32[8192]
#define WS_BASEQ 1146880    // f32[8192]  (enorm + 1024) * 256
#define WS_SUM   1179648    // f32[8192*256] transposed segment sums
#define WS_BINS  9568256    // f32[8192]
#define WS_LOSS  9601024    // f64
#define WS_S     9601032    // f64
#define WS_XB    9601040    // bf16[8192*256]
#define WS_ETB   13795344   // bf16[8192*256] E^T (k-contiguous)
#define WS_ET32  17989648   // f32[8192*256]  E^T
#define WS_ZLEN  (WS_XB - WS_SUM)   // zero sums, bins, loss, S

__device__ __forceinline__ unsigned f32_ord(float f)
{
    unsigned u = __float_as_uint(f);
    return (u & 0x80000000u) ? ~u : (u | 0x80000000u);
}
__device__ __forceinline__ u16 bf16rne(float f)
{
    unsigned u = __float_as_uint(f);
    return (u16)((u + 0x7fffu + ((u >> 16) & 1u)) >> 16);
}
__device__ __forceinline__ void gload16(const void* g, void* l)
{
    __builtin_amdgcn_global_load_lds((const __attribute__((address_space(1))) unsigned int*)g,
                                     (__attribute__((address_space(3))) unsigned int*)l, 16, 0, 0);
}

__global__ __launch_bounds__(256) void vq_cvt_x_k(const float* __restrict__ X, u16* __restrict__ Xb)
{
    const int i = blockIdx.x * 256 + threadIdx.x;
    const float4 a = ((const float4*)X)[i * 2];
    const float4 b = ((const float4*)X)[i * 2 + 1];
    short8 v;
    v[0] = (short)bf16rne(a.x); v[1] = (short)bf16rne(a.y);
    v[2] = (short)bf16rne(a.z); v[3] = (short)bf16rne(a.w);
    v[4] = (short)bf16rne(b.x); v[5] = (short)bf16rne(b.y);
    v[6] = (short)bf16rne(b.z); v[7] = (short)bf16rne(b.w);
    *(short8*)(Xb + (size_t)i * 8) = v;
}

// E [256][8192] -> ET32 [8192][256] f32 + ETb [8192][256] bf16 + enorm/baseq (fused, deterministic)
// One block owns 64 cols j and loops over all 4 d-chunks.
__global__ __launch_bounds__(256) void vq_trans_e_k(const float* __restrict__ E,
                                                    float* __restrict__ ET32,
                                                    u16* __restrict__ ETb,
                                                    float* __restrict__ enorm,
                                                    float* __restrict__ baseq)
{
    __shared__ float T[64][65];
    const int t = threadIdx.x;
    const int j0 = blockIdx.x * 64;
    const int jc = t >> 2, seg = t & 3;
    const int j = j0 + jc;
    float esum = 0.f;

    for (int d0 = 0; d0 < DIM; d0 += 64) {
        if (d0) __syncthreads();          // T reuse: previous reads done
        #pragma unroll
        for (int p = 0; p < 4; ++p) {
            const int dr = p * 16 + (t >> 4);
            const float4 v = *(const float4*)(E + (size_t)(d0 + dr) * NE + j0 + (t & 15) * 4);
            T[dr][(t & 15) * 4 + 0] = v.x; T[dr][(t & 15) * 4 + 1] = v.y;
            T[dr][(t & 15) * 4 + 2] = v.z; T[dr][(t & 15) * 4 + 3] = v.w;
        }
        __syncthreads();
        float vals[16];
        #pragma unroll
        for (int i = 0; i < 16; ++i) vals[i] = T[seg * 16 + i][jc];
        float4* o32 = (float4*)(ET32 + (size_t)j * DIM + d0 + seg * 16);
        o32[0] = make_float4(vals[0], vals[1], vals[2], vals[3]);
        o32[1] = make_float4(vals[4], vals[5], vals[6], vals[7]);
        o32[2] = make_float4(vals[8], vals[9], vals[10], vals[11]);
        o32[3] = make_float4(vals[12], vals[13], vals[14], vals[15]);
        short8 b0, b1;
        #pragma unroll
        for (int i = 0; i < 8; ++i) { b0[i] = (short)bf16rne(vals[i]); b1[i] = (short)bf16rne(vals[8 + i]); }
        *(short8*)(ETb + (size_t)j * DIM + d0 + seg * 16) = b0;
        *(short8*)(ETb + (size_t)j * DIM + d0 + seg * 16 + 8) = b1;
        #pragma unroll
        for (int i = 0; i < 16; ++i) esum += vals[i] * vals[i];
    }
    // threads (jc, seg=0..3) are adjacent lanes: reduce over seg
    esum += __shfl_xor(esum, 1, 4);
    esum += __shfl_xor(esum, 2, 4);
    if (seg == 0) {
        enorm[j] = esum;
        baseq[j] = (esum + 1024.f) * 256.f;
    }
}

// Row-stationary approx scan, 2-phase LDS pipeline. 4 blocks/CU VGPR budget (128) so the
// A-fragments (64 VGPRs) stay register-resident across all 32 tiles.
__global__ __launch_bounds__(256, 4) void vq_scan_k(const u16* __restrict__ Xb,
                                                    const u16* __restrict__ ETb,
                                                    const float* __restrict__ baseq,
                                                    unsigned* __restrict__ cand)
{
    __shared__ u16 Bs[2][8][512]; // [buf][k8-slice][16 cols x 32 k, lane-linear], 8KB/buf

    const int tid = threadIdx.x;
    const int w = tid >> 6, l = tid & 63;
    const int lane16 = l & 15, g = l >> 4;
    const int rowbase = blockIdx.x * 128 + w * 32;
    const int c0 = blockIdx.y * 512;

    // A fragments: lane holds row (l&15) of sub-tile, k-chunk (l>>4)*8, for k8=0..7
    short8 af[2][8];
    #pragma unroll
    for (int sub = 0; sub < 2; ++sub)
        #pragma unroll
        for (int k8 = 0; k8 < 8; ++k8)
            af[sub][k8] = *(const short8*)(Xb + (size_t)(rowbase + sub * 16 + lane16) * DIM + k8 * 32 + g * 8);

    unsigned s0[8], s1[8];
    #pragma unroll
    for (int i = 0; i < 8; ++i) { s0[i] = 0xFFFFFFFFu; s1[i] = 0xFFFFFFFFu; }

    // staging source: wave w owns slices k8 = 2w, 2w+1; lane (g,col) fetches its own 16B
    const u16* gsrc = ETb + (size_t)(c0 + lane16) * DIM + (size_t)w * 64 + g * 8;

    // prologue: stage tile 0
    gload16(gsrc,      &Bs[0][2 * w + 0][0]);
    gload16(gsrc + 32, &Bs[0][2 * w + 1][0]);
    asm volatile("s_waitcnt vmcnt(0)" ::: "memory");
    __builtin_amdgcn_s_barrier();

    int buf = 0;
    #pragma unroll 1
    for (int ct = 0; ct < CTILES; ++ct) {
        if (ct + 1 < CTILES) { // stage next tile into the other buffer (read-done by prev barrier)
            const u16* p = gsrc + (size_t)(ct + 1) * 16 * DIM;
            gload16(p,      &Bs[buf ^ 1][2 * w + 0][0]);
            gload16(p + 32, &Bs[buf ^ 1][2 * w + 1][0]);
        }
        const int col = c0 + ct * 16 + lane16;
        const float bq = baseq[col];
        f32x4 acc0 = {0.f, 0.f, 0.f, 0.f}, acc1 = {0.f, 0.f, 0.f, 0.f};
        #pragma unroll
        for (int k8 = 0; k8 < 8; ++k8) {
            const short8 bf = *(const short8*)&Bs[buf][k8][l * 8];
            acc0 = __builtin_amdgcn_mfma_f32_16x16x32_bf16(af[0][k8], bf, acc0, 0, 0, 0);
            acc1 = __builtin_amdgcn_mfma_f32_16x16x32_bf16(af[1][k8], bf, acc1, 0, 0, 0);
        }
        #pragma unroll
        for (int i = 0; i < 8; ++i) {
            const float a = (i < 4) ? acc0[i] : acc1[i - 4];
            const float qf = fmaf(a, -512.f, bq);       // (enorm - 2*dot + 1024) * 256
            unsigned q = (unsigned)qf;
            q = min(q, 0x7FFFFu);
            const unsigned key = (q << 13) | (unsigned)col;
            const unsigned t = max(s0[i], key);
            s0[i] = min(s0[i], key);
            s1[i] = min(s1[i], t);
        }
        asm volatile("s_waitcnt vmcnt(0)" ::: "memory");
        __builtin_amdgcn_s_barrier();
        buf ^= 1;
    }

    // merge sorted pairs across the 16 lanes of each g-group
    #pragma unroll
    for (int m = 1; m < 16; m <<= 1) {
        #pragma unroll
        for (int i = 0; i < 8; ++i) {
            const unsigned o0 = __shfl_xor(s0[i], m);
            const unsigned o1 = __shfl_xor(s1[i], m);
            const unsigned t0 = min(s0[i], o0);
            const unsigned t1 = min(max(s0[i], o0), min(s1[i], o1));
            s0[i] = t0; s1[i] = t1;
        }
    }
    if (lane16 == 0) {
        #pragma unroll
        for (int i = 0; i < 8; ++i) {
            const int row = rowbase + (i >> 2) * 16 + g * 4 + (i & 3);
            cand[((size_t)row * CRANGES + blockIdx.y) * 2 + 0] = s0[i];
            cand[((size_t)row * CRANGES + blockIdx.y) * 2 + 1] = s1[i];
        }
    }
}

// fused: exact f32 re-rank (one wave per row) + quantize/stats epilogue (256 threads over d)
__global__ __launch_bounds__(256) void vq_finalize_k(const unsigned* __restrict__ cand,
                                                     const float* __restrict__ X,
                                                     const float* __restrict__ ET32,
                                                     const float* __restrict__ enorm,
                                                     float* __restrict__ out_q,
                                                     float* __restrict__ out_ind,
                                                     float* __restrict__ ws_sum,
                                                     float* __restrict__ bins,
                                                     double* __restrict__ loss)
{
    __shared__ int sj[4];
    const int tid = threadIdx.x;
    const int w = tid >> 6, l = tid & 63;
    const int row = blockIdx.x * 4 + w;

    // ---- refine: pick exact argmin among <=32 kept candidates ----
    unsigned key = 0xFFFFFFFFu;
    if (l < 32) key = cand[(size_t)row * 32 + l];
    unsigned qmin = key;
    #pragma unroll
    for (int m = 32; m; m >>= 1) qmin = min(qmin, __shfl_xor(qmin, m));
    const unsigned qthr = (qmin >> 13) + MQ;
    unsigned long long mask = __ballot((l < 32) && ((key >> 13) <= qthr));
    const float4 xv = *(const float4*)(X + (size_t)row * DIM + l * 4);
    unsigned long long best = 0xFFFFFFFFFFFFFFFFull;
    while (mask) {
        const int src = __builtin_ctzll(mask);
        mask &= mask - 1;
        const int col = (int)(__shfl(key, src) & 8191u);
        const float4 ev = *(const float4*)(ET32 + (size_t)col * DIM + l * 4);
        float s = xv.x * ev.x + xv.y * ev.y + xv.z * ev.z + xv.w * ev.w;
        #pragma unroll
        for (int m = 32; m; m >>= 1) s += __shfl_xor(s, m);
        const float d = enorm[col] - 2.f * s;
        const unsigned long long k64 = ((unsigned long long)f32_ord(d) << 32) | (unsigned)col;
        best = (k64 < best) ? k64 : best;
    }
    if (l == 0) {
        const int j = (int)(best & 8191u);
        sj[w] = j;
        out_ind[row] = (float)j;
    }
    __syncthreads();

    // ---- gather/stats: 4 rows, 256 threads over d ----
    float lsum = 0.f;
    #pragma unroll
    for (int q = 0; q < 4; ++q) {
        const int r = blockIdx.x * 4 + q;
        const int j = sj[q];
        const float x  = X[(size_t)r * DIM + tid];
        const float qv = ET32[(size_t)j * DIM + tid];
        out_q[(size_t)r * DIM + tid] = x + (qv - x);
        const float d = qv - x;
        lsum += d * d;
        atomicAdd(&ws_sum[(size_t)j * DIM + tid], x);
        if (tid == 0) atomicAdd(&bins[j], 1.0f);
    }
    #pragma unroll
    for (int off = 32; off > 0; off >>= 1) lsum += __shfl_down(lsum, off);
    __shared__ double wred[4];
    if ((tid & 63) == 0) wred[tid >> 6] = (double)lsum;
    __syncthreads();
    if (tid == 0) atomicAdd(loss, wred[0] + wred[1] + wred[2] + wred[3]);
}

__global__ __launch_bounds__(256) void vq_csn_k(const float* __restrict__ cs,
                                                const float* __restrict__ bins,
                                                float* __restrict__ out_csn,
                                                float* __restrict__ out_loss,
                                                const double* __restrict__ loss,
                                                double* __restrict__ S)
{
    const int tid = threadIdx.x;
    const int i = blockIdx.x * 256 + tid;
    const float csn = cs[i] * DECAY + (1.0f - DECAY) * bins[i];
    out_csn[i] = csn;
    double v = (double)csn;
    #pragma unroll
    for (int off = 32; off > 0; off >>= 1) v += __shfl_down(v, off);
    __shared__ double wred[4];
    if ((tid & 63) == 0) wred[tid >> 6] = v;
    __syncthreads();
    if (tid == 0) atomicAdd(S, wred[0] + wred[1] + wred[2] + wred[3]);
    if (blockIdx.x == 0 && tid == 0) out_loss[0] = (float)(loss[0] * (1.0 / 2097152.0));
}

__global__ __launch_bounds__(256) void vq_embed_k(const float* __restrict__ EA,
                                                  const float* __restrict__ cs,
                                                  const float* __restrict__ bins,
                                                  const float* __restrict__ ws_sum,
                                                  const double* __restrict__ Sp,
                                                  float* __restrict__ out_norm,
                                                  float* __restrict__ out_avg)
{
    __shared__ float T[64][69];
    const int tid = threadIdx.x;
    const int j0 = blockIdx.x * 64;
    const int d0 = blockIdx.y * 64;
    #pragma unroll
    for (int p = 0; p < 4; ++p) {
        const int jr = (tid >> 4) + p * 16;
        const int dc = (tid & 15) * 4;
        const float4 v = *(const float4*)(ws_sum + (size_t)(j0 + jr) * DIM + d0 + dc);
        T[jr][dc + 0] = v.x; T[jr][dc + 1] = v.y; T[jr][dc + 2] = v.z; T[jr][dc + 3] = v.w;
    }
    __syncthreads();
    const double S = Sp[0];
    const float fac = (float)(S / (S + (double)NE * 1e-5));
    const int jc = tid & 63;
    const int j  = j0 + jc;
    const float csn  = cs[j] * DECAY + (1.0f - DECAY) * bins[j];
    const float cs_j = (csn + EPS_F) * fac;
    const int drb = (tid >> 6) * 16;
    #pragma unroll
    for (int p = 0; p < 16; ++p) {
        const int dr = drb + p;
        const float sum = T[jc][dr];
        const float ea  = EA[(size_t)(d0 + dr) * NE + j];
        const float ean = DECAY * ea + (1.0f - DECAY) * sum;
        out_avg[(size_t)(d0 + dr) * NE + j]  = ean;
        out_norm[(size_t)(d0 + dr) * NE + j] = ean / cs_j;
    }
}

extern "C" void kernel_launch(void* const* d_in, const int* in_sizes, int n_in,
                              void* d_out, int out_size, void* d_ws, size_t ws_size,
                              hipStream_t stream)
{
    const float* X  = (const float*)d_in[0];
    const float* E  = (const float*)d_in[1];
    const float* CS = (const float*)d_in[2];
    const float* EA = (const float*)d_in[3];
    float* out = (float*)d_out;
    char*  ws  = (char*)d_ws;

    unsigned* cand  = (unsigned*)(ws + WS_CAND);
    float*  enorm  = (float*)(ws + WS_ENORM);
    float*  baseq  = (float*)(ws + WS_BASEQ);
    float*  ws_sum = (float*)(ws + WS_SUM);
    float*  bins   = (float*)(ws + WS_BINS);
    double* loss   = (double*)(ws + WS_LOSS);
    double* S      = (double*)(ws + WS_S);
    u16*    Xb     = (u16*)(ws + WS_XB);
    u16*    ETb    = (u16*)(ws + WS_ETB);
    float*  ET32   = (float*)(ws + WS_ET32);

    hipMemsetAsync(ws + WS_SUM, 0, WS_ZLEN, stream);   // ws_sum, bins, loss, S

    vq_cvt_x_k<<<1024, 256, 0, stream>>>(X, Xb);
    vq_trans_e_k<<<NE / 64, 256, 0, stream>>>(E, ET32, ETb, enorm, baseq);
    vq_scan_k<<<dim3(NROWS / 128, CRANGES), 256, 0, stream>>>(Xb, ETb, baseq, cand);
    vq_finalize_k<<<NROWS / 4, 256, 0, stream>>>(cand, X, ET32, enorm, out + OUT_Q, out + OUT_IND, ws_sum, bins, loss);
    vq_csn_k<<<NE / 256, 256, 0, stream>>>(CS, bins, out + OUT_CSN, out + OUT_LOSS, loss, S);
    vq_embed_k<<<dim3(NE / 64, DIM / 64), 256, 0, stream>>>(EA, CS, bins, ws_sum, S, out + OUT_NORM, out + OUT_AVG);
}

// Round 7
// 107.094 us; speedup vs baseline: 5.2760x; 1.0839x over previous
//
#include <hip/hip_runtime.h>

typedef unsigned short u16;
typedef __attribute__((ext_vector_type(8))) short short8;
typedef __attribute__((ext_vector_type(4))) float f32x4;

#define DIM    256
#define NE     8192
#define NROWS  8192
#define DECAY  0.1f
#define EPS_F  1e-5f
#define CRANGES 16      // column ranges of 512
#define CTILES  32      // 16-col tiles per range
#define MQ      384u    // refine margin: 1.5 distance units (q step = 1/256)

// output offsets (floats): quantize_st, embed_ind, loss, embed_normalized, cluster_size_new, embed_avg_new
#define OUT_Q    0
#define OUT_IND  2097152
#define OUT_LOSS 2105344
#define OUT_NORM 2105345
#define OUT_CSN  4202497
#define OUT_AVG  4210689

// ws offsets (bytes)
#define WS_CAND  65536      // u32[8192*32] top-2 per (row, range)
#define WS_ENORM 1114112    // f32[8192]
#define WS_BASEQ 1146880    // f32[8192]  (enorm + 512) * 256
#define WS_SUM   1179648    // f32[8192*256] transposed segment sums
#define WS_BINS  9568256    // f32[8192]
#define WS_LOSS  9601024    // f64
#define WS_S     9601032    // f64
#define WS_XB    9601040    // bf16[8192*256]
#define WS_ETB   13795344   // bf16[8192*256] E^T (k-contiguous)
#define WS_ET32  17989648   // f32[8192*256]  E^T
#define WS_ZLEN  (WS_XB - WS_SUM)   // zero sums, bins, loss, S

__device__ __forceinline__ unsigned f32_ord(float f)
{
    unsigned u = __float_as_uint(f);
    return (u & 0x80000000u) ? ~u : (u | 0x80000000u);
}
__device__ __forceinline__ u16 bf16rne(float f)
{
    unsigned u = __float_as_uint(f);
    return (u16)((u + 0x7fffu + ((u >> 16) & 1u)) >> 16);
}
__device__ __forceinline__ void gload16(const void* g, void* l)
{
    __builtin_amdgcn_global_load_lds((const __attribute__((address_space(1))) unsigned int*)g,
                                     (__attribute__((address_space(3))) unsigned int*)l, 16, 0, 0);
}

__global__ __launch_bounds__(256) void vq_cvt_x_k(const float* __restrict__ X, u16* __restrict__ Xb)
{
    const int i = blockIdx.x * 256 + threadIdx.x;
    const float4 a = ((const float4*)X)[i * 2];
    const float4 b = ((const float4*)X)[i * 2 + 1];
    short8 v;
    v[0] = (short)bf16rne(a.x); v[1] = (short)bf16rne(a.y);
    v[2] = (short)bf16rne(a.z); v[3] = (short)bf16rne(a.w);
    v[4] = (short)bf16rne(b.x); v[5] = (short)bf16rne(b.y);
    v[6] = (short)bf16rne(b.z); v[7] = (short)bf16rne(b.w);
    *(short8*)(Xb + (size_t)i * 8) = v;
}

// E [256][8192] -> ET32 [8192][256] f32 + ETb [8192][256] bf16 + enorm/baseq (fused)
__global__ __launch_bounds__(256) void vq_trans_e_k(const float* __restrict__ E,
                                                    float* __restrict__ ET32,
                                                    u16* __restrict__ ETb,
                                                    float* __restrict__ enorm,
                                                    float* __restrict__ baseq)
{
    __shared__ float T[64][65];
    const int t = threadIdx.x;
    const int j0 = blockIdx.x * 64;
    const int jc = t >> 2, seg = t & 3;
    const int j = j0 + jc;
    float esum = 0.f;

    for (int d0 = 0; d0 < DIM; d0 += 64) {
        if (d0) __syncthreads();          // T reuse: previous reads done
        #pragma unroll
        for (int p = 0; p < 4; ++p) {
            const int dr = p * 16 + (t >> 4);
            const float4 v = *(const float4*)(E + (size_t)(d0 + dr) * NE + j0 + (t & 15) * 4);
            T[dr][(t & 15) * 4 + 0] = v.x; T[dr][(t & 15) * 4 + 1] = v.y;
            T[dr][(t & 15) * 4 + 2] = v.z; T[dr][(t & 15) * 4 + 3] = v.w;
        }
        __syncthreads();
        float vals[16];
        #pragma unroll
        for (int i = 0; i < 16; ++i) vals[i] = T[seg * 16 + i][jc];
        float4* o32 = (float4*)(ET32 + (size_t)j * DIM + d0 + seg * 16);
        o32[0] = make_float4(vals[0], vals[1], vals[2], vals[3]);
        o32[1] = make_float4(vals[4], vals[5], vals[6], vals[7]);
        o32[2] = make_float4(vals[8], vals[9], vals[10], vals[11]);
        o32[3] = make_float4(vals[12], vals[13], vals[14], vals[15]);
        short8 b0, b1;
        #pragma unroll
        for (int i = 0; i < 8; ++i) { b0[i] = (short)bf16rne(vals[i]); b1[i] = (short)bf16rne(vals[8 + i]); }
        *(short8*)(ETb + (size_t)j * DIM + d0 + seg * 16) = b0;
        *(short8*)(ETb + (size_t)j * DIM + d0 + seg * 16 + 8) = b1;
        #pragma unroll
        for (int i = 0; i < 16; ++i) esum += vals[i] * vals[i];
    }
    esum += __shfl_xor(esum, 1, 4);
    esum += __shfl_xor(esum, 2, 4);
    if (seg == 0) {
        enorm[j] = esum;
        baseq[j] = (esum + 512.f) * 256.f;
    }
}

// Row-stationary approx scan, 2-phase LDS pipeline.
// Wave owns 64 rows (af[4][8] = 128 VGPRs, pinned resident via empty-asm keepalive);
// block = 4 waves = 256 rows x 512-col range -> 2x less LDS B-read amplification.
// launch_bounds(256,2): 2 blocks/CU, VGPR cap 256 (usage ~195, no spill).
__global__ __launch_bounds__(256, 2) void vq_scan_k(const u16* __restrict__ Xb,
                                                    const u16* __restrict__ ETb,
                                                    const float* __restrict__ baseq,
                                                    unsigned* __restrict__ cand)
{
    __shared__ u16 Bs[2][8][512]; // [buf][k-slice of 32][16 cols x 32 k, lane-linear], 8KB/buf

    const int tid = threadIdx.x;
    const int w = tid >> 6, l = tid & 63;
    const int lane16 = l & 15, g = l >> 4;
    const int rowbase = blockIdx.x * 256 + w * 64;
    const int c0 = blockIdx.y * 512;

    // A fragments: lane holds row (l&15) of sub-tile, k-chunk (l>>4)*8, for k8=0..7.
    // Pinned: the empty asm's output is the only live definition -> compiler cannot
    // rematerialize the global load inside the tile loop (R6: VGPR=56 proved it did).
    short8 af[4][8];
    #pragma unroll
    for (int sub = 0; sub < 4; ++sub)
        #pragma unroll
        for (int k8 = 0; k8 < 8; ++k8) {
            af[sub][k8] = *(const short8*)(Xb + (size_t)(rowbase + sub * 16 + lane16) * DIM + k8 * 32 + g * 8);
            asm volatile("" : "+v"(af[sub][k8]));
        }

    unsigned s0[16], s1[16];
    #pragma unroll
    for (int i = 0; i < 16; ++i) { s0[i] = 0xFFFFFFFFu; s1[i] = 0xFFFFFFFFu; }

    // staging: wave w owns k-slices 2w, 2w+1; lane (g,col) fetches its own 16B
    const u16* gsrc = ETb + (size_t)(c0 + lane16) * DIM + (size_t)w * 64 + g * 8;

    // prologue: stage tile 0
    gload16(gsrc,      &Bs[0][2 * w + 0][0]);
    gload16(gsrc + 32, &Bs[0][2 * w + 1][0]);
    asm volatile("s_waitcnt vmcnt(0)" ::: "memory");
    __builtin_amdgcn_s_barrier();

    int buf = 0;
    #pragma unroll 1
    for (int ct = 0; ct < CTILES; ++ct) {
        if (ct + 1 < CTILES) { // stage next tile into the other buffer
            const u16* p = gsrc + (size_t)(ct + 1) * 16 * DIM;
            gload16(p,      &Bs[buf ^ 1][2 * w + 0][0]);
            gload16(p + 32, &Bs[buf ^ 1][2 * w + 1][0]);
        }
        const int col = c0 + ct * 16 + lane16;
        const float bq = baseq[col];
        f32x4 acc[4];
        #pragma unroll
        for (int sub = 0; sub < 4; ++sub) acc[sub] = {0.f, 0.f, 0.f, 0.f};
        #pragma unroll
        for (int k8 = 0; k8 < 8; ++k8) {
            const short8 bf = *(const short8*)&Bs[buf][k8][l * 8];
            #pragma unroll
            for (int sub = 0; sub < 4; ++sub)
                acc[sub] = __builtin_amdgcn_mfma_f32_16x16x32_bf16(af[sub][k8], bf, acc[sub], 0, 0, 0);
        }
        #pragma unroll
        for (int sub = 0; sub < 4; ++sub)
            #pragma unroll
            for (int r = 0; r < 4; ++r) {
                const int i = sub * 4 + r;
                const float qf = fmaf(acc[sub][r], -512.f, bq);  // (enorm - 2*dot + 512) * 256
                const unsigned key = (((unsigned)qf) << 13) | (unsigned)col;
                const unsigned t = max(s0[i], key);
                s0[i] = min(s0[i], key);
                s1[i] = min(s1[i], t);
            }
        asm volatile("s_waitcnt vmcnt(0)" ::: "memory");
        __builtin_amdgcn_s_barrier();
        buf ^= 1;
    }

    // merge sorted pairs across the 16 lanes of each g-group
    #pragma unroll
    for (int m = 1; m < 16; m <<= 1) {
        #pragma unroll
        for (int i = 0; i < 16; ++i) {
            const unsigned o0 = __shfl_xor(s0[i], m);
            const unsigned o1 = __shfl_xor(s1[i], m);
            const unsigned t0 = min(s0[i], o0);
            const unsigned t1 = min(max(s0[i], o0), min(s1[i], o1));
            s0[i] = t0; s1[i] = t1;
        }
    }
    if (lane16 == 0) {
        #pragma unroll
        for (int i = 0; i < 16; ++i) {
            const int row = rowbase + (i >> 2) * 16 + g * 4 + (i & 3);
            cand[((size_t)row * CRANGES + blockIdx.y) * 2 + 0] = s0[i];
            cand[((size_t)row * CRANGES + blockIdx.y) * 2 + 1] = s1[i];
        }
    }
}

// fused: exact f32 re-rank (one wave per row) + quantize/stats epilogue (256 threads over d)
__global__ __launch_bounds__(256) void vq_finalize_k(const unsigned* __restrict__ cand,
                                                     const float* __restrict__ X,
                                                     const float* __restrict__ ET32,
                                                     const float* __restrict__ enorm,
                                                     float* __restrict__ out_q,
                                                     float* __restrict__ out_ind,
                                                     float* __restrict__ ws_sum,
                                                     float* __restrict__ bins,
                                                     double* __restrict__ loss)
{
    __shared__ int sj[4];
    const int tid = threadIdx.x;
    const int w = tid >> 6, l = tid & 63;
    const int row = blockIdx.x * 4 + w;

    unsigned key = 0xFFFFFFFFu;
    if (l < 32) key = cand[(size_t)row * 32 + l];
    unsigned qmin = key;
    #pragma unroll
    for (int m = 32; m; m >>= 1) qmin = min(qmin, __shfl_xor(qmin, m));
    const unsigned qthr = (qmin >> 13) + MQ;
    unsigned long long mask = __ballot((l < 32) && ((key >> 13) <= qthr));
    const float4 xv = *(const float4*)(X + (size_t)row * DIM + l * 4);
    unsigned long long best = 0xFFFFFFFFFFFFFFFFull;
    while (mask) {
        const int src = __builtin_ctzll(mask);
        mask &= mask - 1;
        const int col = (int)(__shfl(key, src) & 8191u);
        const float4 ev = *(const float4*)(ET32 + (size_t)col * DIM + l * 4);
        float s = xv.x * ev.x + xv.y * ev.y + xv.z * ev.z + xv.w * ev.w;
        #pragma unroll
        for (int m = 32; m; m >>= 1) s += __shfl_xor(s, m);
        const float d = enorm[col] - 2.f * s;
        const unsigned long long k64 = ((unsigned long long)f32_ord(d) << 32) | (unsigned)col;
        best = (k64 < best) ? k64 : best;
    }
    if (l == 0) {
        const int j = (int)(best & 8191u);
        sj[w] = j;
        out_ind[row] = (float)j;
    }
    __syncthreads();

    float lsum = 0.f;
    #pragma unroll
    for (int q = 0; q < 4; ++q) {
        const int r = blockIdx.x * 4 + q;
        const int j = sj[q];
        const float x  = X[(size_t)r * DIM + tid];
        const float qv = ET32[(size_t)j * DIM + tid];
        out_q[(size_t)r * DIM + tid] = x + (qv - x);
        const float d = qv - x;
        lsum += d * d;
        atomicAdd(&ws_sum[(size_t)j * DIM + tid], x);
        if (tid == 0) atomicAdd(&bins[j], 1.0f);
    }
    #pragma unroll
    for (int off = 32; off > 0; off >>= 1) lsum += __shfl_down(lsum, off);
    __shared__ double wred[4];
    if ((tid & 63) == 0) wred[tid >> 6] = (double)lsum;
    __syncthreads();
    if (tid == 0) atomicAdd(loss, wred[0] + wred[1] + wred[2] + wred[3]);
}

__global__ __launch_bounds__(256) void vq_csn_k(const float* __restrict__ cs,
                                                const float* __restrict__ bins,
                                                float* __restrict__ out_csn,
                                                float* __restrict__ out_loss,
                                                const double* __restrict__ loss,
                                                double* __restrict__ S)
{
    const int tid = threadIdx.x;
    const int i = blockIdx.x * 256 + tid;
    const float csn = cs[i] * DECAY + (1.0f - DECAY) * bins[i];
    out_csn[i] = csn;
    double v = (double)csn;
    #pragma unroll
    for (int off = 32; off > 0; off >>= 1) v += __shfl_down(v, off);
    __shared__ double wred[4];
    if ((tid & 63) == 0) wred[tid >> 6] = v;
    __syncthreads();
    if (tid == 0) atomicAdd(S, wred[0] + wred[1] + wred[2] + wred[3]);
    if (blockIdx.x == 0 && tid == 0) out_loss[0] = (float)(loss[0] * (1.0 / 2097152.0));
}

__global__ __launch_bounds__(256) void vq_embed_k(const float* __restrict__ EA,
                                                  const float* __restrict__ cs,
                                                  const float* __restrict__ bins,
                                                  const float* __restrict__ ws_sum,
                                                  const double* __restrict__ Sp,
                                                  float* __restrict__ out_norm,
                                                  float* __restrict__ out_avg)
{
    __shared__ float T[64][69];
    const int tid = threadIdx.x;
    const int j0 = blockIdx.x * 64;
    const int d0 = blockIdx.y * 64;
    #pragma unroll
    for (int p = 0; p < 4; ++p) {
        const int jr = (tid >> 4) + p * 16;
        const int dc = (tid & 15) * 4;
        const float4 v = *(const float4*)(ws_sum + (size_t)(j0 + jr) * DIM + d0 + dc);
        T[jr][dc + 0] = v.x; T[jr][dc + 1] = v.y; T[jr][dc + 2] = v.z; T[jr][dc + 3] = v.w;
    }
    __syncthreads();
    const double S = Sp[0];
    const float fac = (float)(S / (S + (double)NE * 1e-5));
    const int jc = tid & 63;
    const int j  = j0 + jc;
    const float csn  = cs[j] * DECAY + (1.0f - DECAY) * bins[j];
    const float cs_j = (csn + EPS_F) * fac;
    const int drb = (tid >> 6) * 16;
    #pragma unroll
    for (int p = 0; p < 16; ++p) {
        const int dr = drb + p;
        const float sum = T[jc][dr];
        const float ea  = EA[(size_t)(d0 + dr) * NE + j];
        const float ean = DECAY * ea + (1.0f - DECAY) * sum;
        out_avg[(size_t)(d0 + dr) * NE + j]  = ean;
        out_norm[(size_t)(d0 + dr) * NE + j] = ean / cs_j;
    }
}

extern "C" void kernel_launch(void* const* d_in, const int* in_sizes, int n_in,
                              void* d_out, int out_size, void* d_ws, size_t ws_size,
                              hipStream_t stream)
{
    const float* X  = (const float*)d_in[0];
    const float* E  = (const float*)d_in[1];
    const float* CS = (const float*)d_in[2];
    const float* EA = (const float*)d_in[3];
    float* out = (float*)d_out;
    char*  ws  = (char*)d_ws;

    unsigned* cand  = (unsigned*)(ws + WS_CAND);
    float*  enorm  = (float*)(ws + WS_ENORM);
    float*  baseq  = (float*)(ws + WS_BASEQ);
    float*  ws_sum = (float*)(ws + WS_SUM);
    float*  bins   = (float*)(ws + WS_BINS);
    double* loss   = (double*)(ws + WS_LOSS);
    double* S      = (double*)(ws + WS_S);
    u16*    Xb     = (u16*)(ws + WS_XB);
    u16*    ETb    = (u16*)(ws + WS_ETB);
    float*  ET32   = (float*)(ws + WS_ET32);

    hipMemsetAsync(ws + WS_SUM, 0, WS_ZLEN, stream);   // ws_sum, bins, loss, S

    vq_cvt_x_k<<<1024, 256, 0, stream>>>(X, Xb);
    vq_trans_e_k<<<NE / 64, 256, 0, stream>>>(E, ET32, ETb, enorm, baseq);
    vq_scan_k<<<dim3(NROWS / 256, CRANGES), 256, 0, stream>>>(Xb, ETb, baseq, cand);
    vq_finalize_k<<<NROWS / 4, 256, 0, stream>>>(cand, X, ET32, enorm, out + OUT_Q, out + OUT_IND, ws_sum, bins, loss);
    vq_csn_k<<<NE / 256, 256, 0, stream>>>(CS, bins, out + OUT_CSN, out + OUT_LOSS, loss, S);
    vq_embed_k<<<dim3(NE / 64, DIM / 64), 256, 0, stream>>>(EA, CS, bins, ws_sum, S, out + OUT_NORM, out + OUT_AVG);
}